// Round 1
// baseline (652.922 us; speedup 1.0000x reference)
//
#include <hip/hip_runtime.h>

#define B_SZ   32768
#define H_SZ   256
#define E_SZ   128
#define K_CH   8
#define XH_K   384      // E + H
#define N_G    768      // 3 gates * H  (i, o, c~)

typedef __attribute__((ext_vector_type(8))) short  short8;
typedef __attribute__((ext_vector_type(4))) short  s16x4;
typedef __attribute__((ext_vector_type(4))) float  f32x4;

// fp32 -> bf16, round-to-nearest-even
static __device__ __forceinline__ short f2bf(float f) {
  union { float f; unsigned u; } v; v.f = f;
  unsigned u = v.u;
  return (short)((u + 0x7fffu + ((u >> 16) & 1u)) >> 16);
}

static __device__ __forceinline__ float bf2f(short s) {
  union { unsigned u; float f; } v;
  v.u = ((unsigned)(unsigned short)s) << 16;
  return v.f;
}

static __device__ __forceinline__ float sigmoid_f(float x) {
  return 1.0f / (1.0f + __expf(-x));
}

static __device__ __forceinline__ float tanh_f(float x) {
  float xc = fminf(fmaxf(x, -40.0f), 40.0f);
  float e  = __expf(2.0f * xc);
  return (e - 1.0f) / (e + 1.0f);
}

// async global->LDS, 16 B per lane; LDS dst must be wave-uniform base
static __device__ __forceinline__ void gload_lds16(const short* g, short* l) {
  __builtin_amdgcn_global_load_lds(
      (const __attribute__((address_space(1))) unsigned int*)g,
      (__attribute__((address_space(3))) unsigned int*)l, 16, 0, 0);
}

// ---------------- Kernel 1: xh = concat(embed[x], h_pre) as bf16 -----------
__global__ __launch_bounds__(256) void prep_xh(const int* __restrict__ x,
                                               const float* __restrict__ h_pre,
                                               const float* __restrict__ emb,
                                               short* __restrict__ xh) {
  int t = blockIdx.x * 256 + threadIdx.x;
  int b = t / 96;
  int c = (t - b * 96) * 4;
  f32x4 v;
  if (c < E_SZ) {
    int row = x[b];
    v = *(const f32x4*)(emb + (size_t)row * E_SZ + c);
  } else {
    v = *(const f32x4*)(h_pre + (size_t)b * H_SZ + (c - E_SZ));
  }
  s16x4 o;
#pragma unroll
  for (int i = 0; i < 4; ++i) o[i] = f2bf(v[i]);
  *(s16x4*)(xh + (size_t)b * XH_K + c) = o;
}

// ---------------- Kernel 2: Wcat = [Wi; Wo; Wc] as bf16 --------------------
__global__ __launch_bounds__(256) void prep_w(const float* __restrict__ Wi,
                                              const float* __restrict__ Wo,
                                              const float* __restrict__ Wc,
                                              short* __restrict__ Wcat) {
  int t = blockIdx.x * 256 + threadIdx.x;   // N_G * 96 threads
  int n = t / 96;
  int c = (t - n * 96) * 4;
  const float* src = (n < H_SZ)     ? (Wi + (size_t)n * XH_K)
                   : (n < 2 * H_SZ) ? (Wo + (size_t)(n - H_SZ) * XH_K)
                                    : (Wc + (size_t)(n - 2 * H_SZ) * XH_K);
  f32x4 v = *(const f32x4*)(src + c);
  s16x4 o;
#pragma unroll
  for (int i = 0; i < 4; ++i) o[i] = f2bf(v[i]);
  *(s16x4*)(Wcat + (size_t)n * XH_K + c) = o;
}

// ---------------- Kernel 3: gates = act(xh @ Wcat^T + bias) as bf16 --------
// 128x128 block tile, BK=64 (6 K-steps, half the barriers of BK=32).
// LDS staged via global_load_lds(16B) with XOR slot-swizzle applied on the
// GLOBAL source address (LDS stays linear as gload_lds requires); matching
// XOR on the ds_read side. Row stride is 128 B (bank-period-aligned), the
// slot^(row&7) swizzle spreads 8 consecutive rows over all 8 16B slots ->
// 2-way conflict only (free).
__global__ __launch_bounds__(256) void gemm_gates(const short* __restrict__ xh,
                                                  const short* __restrict__ Wcat,
                                                  const float* __restrict__ bi,
                                                  const float* __restrict__ bo,
                                                  const float* __restrict__ bc,
                                                  short* __restrict__ gates) {
  __shared__ short As[128 * 64];   // 16 KB, [row][64] with slot-swizzled cols
  __shared__ short Bs[128 * 64];   // 16 KB

  const int wave = threadIdx.x >> 6;
  const int lane = threadIdx.x & 63;
  const int ln = lane & 15;        // col / row-in-16
  const int q  = lane >> 4;        // quad: k = q*8 + j ; D row = q*4 + r
  const int m0 = blockIdx.y * 128 + (wave >> 1) * 64;
  const int n0 = blockIdx.x * 128 + (wave & 1) * 64;
  const int Am = blockIdx.y * 128; // block A origin
  const int Bn = blockIdx.x * 128; // block B origin

  f32x4 acc[4][4] = {};

  for (int ks = 0; ks < 6; ++ks) {
    if (ks) __syncthreads();            // protect LDS from prior readers
    // stage A and B tiles: 1024 chunks of 16 B each per tile.
    // LDS is linear: chunk index = seg, LDS offset = seg*16 B.
    // seg -> row = seg>>3, slot = seg&7; the global chunk fetched into
    // (row, slot) is slot ^ (row&7)  (involution; reader applies same XOR).
#pragma unroll
    for (int s = 0; s < 4; ++s) {
      const int segb = s * 256 + wave * 64;      // wave-uniform
      const int seg  = segb + lane;
      const int row  = seg >> 3;
      const int ch8  = ((seg & 7) ^ (row & 7)) * 8;
      gload_lds16(xh   + (size_t)(Am + row) * XH_K + ks * 64 + ch8, &As[segb * 8]);
      gload_lds16(Wcat + (size_t)(Bn + row) * XH_K + ks * 64 + ch8, &Bs[segb * 8]);
    }
    __syncthreads();                    // barrier drains vmcnt

    short8 a[2][4], b[2][4];
    const int mw = (wave >> 1) * 64;    // wave offset within block tile
    const int nw = (wave & 1) * 64;
#pragma unroll
    for (int kk = 0; kk < 2; ++kk) {
#pragma unroll
      for (int i = 0; i < 4; ++i) {
        const int r = mw + i * 16 + ln;
        a[kk][i] = *(const short8*)&As[r * 64 + (((kk * 4 + q) ^ (r & 7)) * 8)];
      }
#pragma unroll
      for (int j = 0; j < 4; ++j) {
        const int r = nw + j * 16 + ln;
        b[kk][j] = *(const short8*)&Bs[r * 64 + (((kk * 4 + q) ^ (r & 7)) * 8)];
      }
    }
#pragma unroll
    for (int kk = 0; kk < 2; ++kk)
#pragma unroll
      for (int i = 0; i < 4; ++i)
#pragma unroll
        for (int j = 0; j < 4; ++j)
          acc[i][j] = __builtin_amdgcn_mfma_f32_16x16x32_bf16(a[kk][i], b[kk][j], acc[i][j], 0, 0, 0);
  }

#pragma unroll
  for (int j = 0; j < 4; ++j) {
    const int col  = n0 + j * 16 + ln;
    const int gate = col >> 8;          // 0:i(sig) 1:o(sig) 2:c~(tanh)
    const int cc   = col & 255;
    const float bias = (gate == 0) ? bi[cc] : (gate == 1) ? bo[cc] : bc[cc];
#pragma unroll
    for (int i = 0; i < 4; ++i) {
#pragma unroll
      for (int r = 0; r < 4; ++r) {
        const int row = m0 + i * 16 + q * 4 + r;
        float v = acc[i][j][r] + bias;
        v = (gate == 2) ? tanh_f(v) : sigmoid_f(v);
        gates[(size_t)row * N_G + col] = f2bf(v);
      }
    }
  }
}

// ---------------- Kernel 4: softmax-combine over [i; child_w] -------------
// Streaming (no max-subtraction: weights ~N(0,1), i in (0,1) -> exp <= ~300,
// safe in fp32). One thread per (b, 4h): ALL 16 child loads (8k x {w,l})
// are issued into registers before any compute -> 16-deep MLP per thread
// (the previous version was VGPR-capped at 36 and serialized its k-loop).
__global__ __launch_bounds__(256) void combine(const short* __restrict__ gates,
                                               const float* __restrict__ ccells,
                                               const float* __restrict__ cweights,
                                               float* __restrict__ out) {
  int t = blockIdx.x * 256 + threadIdx.x;   // B*64 threads
  int b = t >> 6;
  int h = (t & 63) * 4;
  const short* grow = gates + (size_t)b * N_G;

  // prefetch all child data: 16 independent 16 B loads in flight
  f32x4 w[K_CH], l[K_CH];
#pragma unroll
  for (int k = 0; k < K_CH; ++k) {
    size_t off = ((size_t)k * B_SZ + b) * H_SZ + h;
    w[k] = *(const f32x4*)(cweights + off);
    l[k] = *(const f32x4*)(ccells + off);
  }
  s16x4 ig = *(const s16x4*)(grow + h);
  s16x4 og = *(const s16x4*)(grow + H_SZ + h);
  s16x4 cg = *(const s16x4*)(grow + 2 * H_SZ + h);

  // own candidate seeds the accumulation
  f32x4 num, den;
#pragma unroll
  for (int c = 0; c < 4; ++c) {
    float e = __expf(bf2f(ig[c]));
    num[c] = e * bf2f(cg[c]);
    den[c] = e;
  }

#pragma unroll
  for (int k = 0; k < K_CH; ++k) {
#pragma unroll
    for (int c = 0; c < 4; ++c) {
      float e = __expf(w[k][c]);
      num[c] += e * l[k][c];
      den[c] += e;
    }
  }

  f32x4 hv, cc;
#pragma unroll
  for (int c = 0; c < 4; ++c) {
    cc[c] = num[c] / den[c];
    hv[c] = bf2f(og[c]) * tanh_f(cc[c]);
  }
  float* oh = out + (size_t)b * H_SZ + h;
  float* oc = out + (size_t)B_SZ * H_SZ + (size_t)b * H_SZ + h;
  *(f32x4*)oh = hv;
  *(f32x4*)oc = cc;
}

extern "C" void kernel_launch(void* const* d_in, const int* in_sizes, int n_in,
                              void* d_out, int out_size, void* d_ws, size_t ws_size,
                              hipStream_t stream) {
  const int*   x             = (const int*)d_in[0];
  const float* h_pre         = (const float*)d_in[1];
  // d_in[2] = c_pre : unused by the reference
  const float* child_cells   = (const float*)d_in[3];
  const float* child_weights = (const float*)d_in[4];
  const float* emb           = (const float*)d_in[5];
  // d_in[6] = Wf, d_in[7] = bf : dead code in the reference (f never used)
  const float* Wi            = (const float*)d_in[8];
  const float* bi            = (const float*)d_in[9];
  const float* Wo            = (const float*)d_in[10];
  const float* bo            = (const float*)d_in[11];
  const float* Wc            = (const float*)d_in[12];
  const float* bc            = (const float*)d_in[13];
  float* out = (float*)d_out;

  char* ws = (char*)d_ws;
  short* xh    = (short*)ws;                                  // B*384 bf16 = 25.2 MB
  short* Wcat  = (short*)(ws + (size_t)B_SZ * XH_K * 2);      // 768*384 bf16
  short* gates = (short*)(ws + (size_t)B_SZ * XH_K * 2
                             + (size_t)N_G * XH_K * 2);       // B*768 bf16 = 50.3 MB

  prep_xh<<<dim3(B_SZ * 96 / 256), dim3(256), 0, stream>>>(x, h_pre, emb, xh);
  prep_w <<<dim3(N_G * 96 / 256),  dim3(256), 0, stream>>>(Wi, Wo, Wc, Wcat);
  gemm_gates<<<dim3(6, 256), dim3(256), 0, stream>>>(xh, Wcat, bi, bo, bc, gates);
  combine<<<dim3(B_SZ * 64 / 256), dim3(256), 0, stream>>>(gates, child_cells, child_weights, out);
}